// Round 3
// baseline (844.512 us; speedup 1.0000x reference)
//
#include <hip/hip_runtime.h>
#include <hip/hip_bf16.h>

// ---------------------------------------------------------------------------
// EDACrossIMUEncoder fused forward (MI355X / gfx950)
//
// Seq-len == 1  =>  softmax(1x1) == 1  =>  MHA(q,k) == k @ (Wo Wv)^T + (Wo bv + bo).
// Whole network = per-row chain of small GEMMs + LayerNorms; fused into ONE
// main kernel. One wave owns 64 batch rows (2x 32-row MFMA tiles, MR=2 B-reuse).
// Weights pre-packed (2 prep kernels) into bf16 MFMA-B-fragment order in d_ws.
// 32x32x16 bf16 MFMA layouts (learn_hip m74/m101 verified):
//   A: row = lane&31, k = (lane>>5)*8 + j   (8 contiguous bf16 = 1 dwordx4)
//   B: col = lane&31, k = (lane>>5)*8 + j
//   C/D: col = lane&31, row = (r&3) + 8*(r>>2) + 4*(lane>>5), r = 0..15
// HBM floor: 256MB tokens + 32MB out ~= 46us @ 6.3TB/s.
// Requires ws_size >= 1.25 MB.
// ---------------------------------------------------------------------------

typedef __bf16 bf16x8_t __attribute__((ext_vector_type(8)));
typedef float  f32x16_t __attribute__((ext_vector_type(16)));
typedef float  f32x4_t  __attribute__((ext_vector_type(4)));

#define DEV static __device__ __forceinline__

DEV f32x16_t mfma_op(bf16x8_t a, bf16x8_t b, f32x16_t c) {
  return __builtin_amdgcn_mfma_f32_32x32x16_bf16(a, b, c, 0, 0, 0);
}

DEV bf16x8_t cvt8(const float* p) {
  f32x4_t t0 = *(const f32x4_t*)p;
  f32x4_t t1 = *(const f32x4_t*)(p + 4);
  bf16x8_t a;
  a[0] = (__bf16)t0[0]; a[1] = (__bf16)t0[1]; a[2] = (__bf16)t0[2]; a[3] = (__bf16)t0[3];
  a[4] = (__bf16)t1[0]; a[5] = (__bf16)t1[1]; a[6] = (__bf16)t1[2]; a[7] = (__bf16)t1[3];
  return a;
}

// ---- packed-weight element offsets (bf16 elems; one chunk = 64 lanes x 8 = 512) ----
constexpr int PO_PROJ_E = 0;                     // K=512 N=128 : 128 chunks
constexpr int PO_PROJ_I = PO_PROJ_E + 128 * 512;
constexpr int PO_ATTN   = PO_PROJ_I + 128 * 512; // 4 x (K=128 N=128 : 32 chunks) [e2i l0, e2i l1, i2e l0, i2e l1]
constexpr int PO_FFN1   = PO_ATTN   + 4 * 32 * 512; // 4 x (K=128 N=256 : 64 chunks) [eda l0, eda l1, imu l0, imu l1]
constexpr int PO_FFN2   = PO_FFN1   + 4 * 64 * 512; // 4 x (K=256 N=128 : 64 chunks)
constexpr int PO_HEAD   = PO_FFN2   + 4 * 64 * 512; // K=256 N=128 : 64 chunks
constexpr int WS_BC_F      = 4 * 128 * 128;          // float index of combined bias region
constexpr int WS_PACK_BYTE = (WS_BC_F + 4 * 128) * 4; // = 264192 (16B aligned)

#define PITCH_S 136   // bf16 elems per row of state scratch (128 + 8 pad); 272B = 17*16
#define PITCH_H 40    // bf16 elems per row of FFN-h scratch  (32 + 8 pad);  80B = 5*16

// ---------------------------------------------------------------------------
// prep 1: fold attention:  Wc = Wo @ Wv (f32),  bc = Wo @ bv + bo
// grid 512 x 64 : block = (d*128 + n), d in {e2i l0, e2i l1, i2e l0, i2e l1}
// ---------------------------------------------------------------------------
__global__ __launch_bounds__(64) void prep_combine(
    const float* __restrict__ e2i_wqkv, const float* __restrict__ e2i_wo,
    const float* __restrict__ e2i_bqkv, const float* __restrict__ e2i_bo,
    const float* __restrict__ i2e_wqkv, const float* __restrict__ i2e_wo,
    const float* __restrict__ i2e_bqkv, const float* __restrict__ i2e_bo,
    float* __restrict__ wsf) {
  const int blk = blockIdx.x;
  const int d = blk >> 7, n = blk & 127, l = d & 1;
  const float* wqkv = (d < 2) ? e2i_wqkv : i2e_wqkv;
  const float* wo   = (d < 2) ? e2i_wo   : i2e_wo;
  const float* bqkv = (d < 2) ? e2i_bqkv : i2e_bqkv;
  const float* bo   = (d < 2) ? e2i_bo   : i2e_bo;
  const float* wv    = wqkv + l * 3 * 128 * 128 + 2 * 128 * 128; // wqkv[2M:3M]
  const float* worow = wo + l * 128 * 128 + n * 128;
  const float* bv    = bqkv + l * 3 * 128 + 2 * 128;
  const int lane = threadIdx.x;
  float a0 = 0.f, a1 = 0.f;
  for (int p = 0; p < 128; ++p) {
    float w = worow[p];
    a0 += w * wv[p * 128 + lane];
    a1 += w * wv[p * 128 + 64 + lane];
  }
  wsf[d * 16384 + n * 128 + lane]      = a0;
  wsf[d * 16384 + n * 128 + 64 + lane] = a1;
  float bacc = worow[lane] * bv[lane] + worow[64 + lane] * bv[64 + lane];
  for (int off = 1; off < 64; off <<= 1) bacc += __shfl_xor(bacc, off, 64);
  if (lane == 0) wsf[WS_BC_F + d * 128 + n] = bacc + bo[l * 128 + n];
}

// ---------------------------------------------------------------------------
// prep 2: pack all weights into bf16 B-fragment order.
// One block (64 thr) packs one 1KB chunk: dst[(chunk*64 + lane)*8 + j] =
//   bf16( W[n = nt*32 + (lane&31)][k = kt*16 + (lane>>5)*8 + j] ), chunk = kt*NT+nt
// grid 960 blocks.
// ---------------------------------------------------------------------------
__global__ __launch_bounds__(64) void prep_pack(
    const float* __restrict__ proj_e, const float* __restrict__ proj_i,
    const float* __restrict__ ffn_e_w1, const float* __restrict__ ffn_i_w1,
    const float* __restrict__ ffn_e_w2, const float* __restrict__ ffn_i_w2,
    const float* __restrict__ out_w, const float* __restrict__ wsf,
    __bf16* __restrict__ pack) {
  const int b = blockIdx.x, lane = threadIdx.x;
  const float* src; int K, sh, dstOff, c; // sh: log2(NT)
  if (b < 128)      { src = proj_e; K = 512; sh = 2; dstOff = PO_PROJ_E; c = b; }
  else if (b < 256) { src = proj_i; K = 512; sh = 2; dstOff = PO_PROJ_I; c = b - 128; }
  else if (b < 384) { int i = (b - 256) >> 5; c = (b - 256) & 31;
                      src = wsf + i * 16384; K = 128; sh = 2;
                      dstOff = PO_ATTN + i * 32 * 512; }
  else if (b < 640) { int i = (b - 384) >> 6; c = (b - 384) & 63;
                      src = ((i < 2) ? ffn_e_w1 : ffn_i_w1) + (i & 1) * 256 * 128;
                      K = 128; sh = 3; dstOff = PO_FFN1 + i * 64 * 512; }
  else if (b < 896) { int i = (b - 640) >> 6; c = (b - 640) & 63;
                      src = ((i < 2) ? ffn_e_w2 : ffn_i_w2) + (i & 1) * 128 * 256;
                      K = 256; sh = 2; dstOff = PO_FFN2 + i * 64 * 512; }
  else              { c = b - 896; src = out_w; K = 256; sh = 2; dstOff = PO_HEAD; }
  const int kt = c >> sh, nt = c & ((1 << sh) - 1);
  const int n  = nt * 32 + (lane & 31);
  const int kb = kt * 16 + (lane >> 5) * 8;
  const float* s = src + n * K + kb;
  bf16x8_t v;
#pragma unroll
  for (int j = 0; j < 8; ++j) v[j] = (__bf16)s[j];
  *(bf16x8_t*)&pack[dstOff + (c * 64 + lane) * 8] = v;
}

// ---------------------------------------------------------------------------
// main fused kernel: 1024 blocks x 64 threads (1 wave = 64 batch rows).
// LDS 39936B -> 4 blocks/CU. No __syncthreads (single-wave blocks).
// ---------------------------------------------------------------------------
__global__ __launch_bounds__(64, 1) void fused_fwd(
    const float* __restrict__ tokens,
    const float* __restrict__ eda_proj_b, const float* __restrict__ eda_cls,
    const float* __restrict__ imu_proj_b, const float* __restrict__ imu_cls,
    const float* __restrict__ ffn_eda_b1, const float* __restrict__ ffn_eda_b2,
    const float* __restrict__ ffn_imu_b1, const float* __restrict__ ffn_imu_b2,
    const float* __restrict__ ln_e1g, const float* __restrict__ ln_e1b,
    const float* __restrict__ ln_e2g, const float* __restrict__ ln_e2b,
    const float* __restrict__ ln_i1g, const float* __restrict__ ln_i1b,
    const float* __restrict__ ln_i2g, const float* __restrict__ ln_i2b,
    const float* __restrict__ out_b, const float* __restrict__ out_ln_g,
    const float* __restrict__ out_ln_b,
    const float* __restrict__ bc_all,          // [4][128] combined attn bias
    const __bf16* __restrict__ pack,
    float* __restrict__ out) {
  alignas(16) __shared__ __bf16 smem[2 * 64 * PITCH_S + 64 * PITCH_H];
  __bf16* Se = smem;
  __bf16* Si = smem + 64 * PITCH_S;
  __bf16* Sh = smem + 2 * 64 * PITCH_S;

  const int lane = threadIdx.x;
  const int l31 = lane & 31, lh = lane >> 5;
  const int rowbase = blockIdx.x * 64;

  auto crowf = [&](int r) { return (r & 3) + ((r >> 2) << 3) + (lh << 2); };

  auto layer_norm = [&](f32x16_t (&A)[2][4], const float* g, const float* bb) {
    float gv[4], bv[4];
#pragma unroll
    for (int nt = 0; nt < 4; ++nt) { gv[nt] = g[nt * 32 + l31]; bv[nt] = bb[nt * 32 + l31]; }
#pragma unroll
    for (int mr = 0; mr < 2; ++mr)
#pragma unroll
      for (int r = 0; r < 16; ++r) {
        float s = 0.f, s2 = 0.f;
#pragma unroll
        for (int nt = 0; nt < 4; ++nt) { float v = A[mr][nt][r]; s += v; s2 += v * v; }
#pragma unroll
        for (int off = 1; off < 32; off <<= 1) {
          s  += __shfl_xor(s, off, 64);
          s2 += __shfl_xor(s2, off, 64);
        }
        const float mean = s * (1.f / 128.f);
        const float var  = s2 * (1.f / 128.f) - mean * mean;
        const float rs   = rsqrtf(var + 1e-5f);
#pragma unroll
        for (int nt = 0; nt < 4; ++nt)
          A[mr][nt][r] = (A[mr][nt][r] - mean) * rs * gv[nt] + bv[nt];
      }
  };

  auto store_state = [&](f32x16_t (&A)[2][4], __bf16* S) {
#pragma unroll
    for (int mr = 0; mr < 2; ++mr)
#pragma unroll
      for (int nt = 0; nt < 4; ++nt)
#pragma unroll
        for (int r = 0; r < 16; ++r)
          S[(mr * 32 + crowf(r)) * PITCH_S + nt * 32 + l31] = (__bf16)A[mr][nt][r];
  };

  // ---------------- projections: state = tok @ Wproj^T + b + cls ----------------
  for (int sel = 0; sel < 2; ++sel) {
    const float* pb = sel ? imu_proj_b : eda_proj_b;
    const float* pc = sel ? imu_cls : eda_cls;
    __bf16* Sd = sel ? Si : Se;
    const int po = sel ? PO_PROJ_I : PO_PROJ_E;
    f32x16_t acc[2][4] = {};
    const float* t0 = tokens + (size_t)(rowbase + l31) * 1024 + sel * 512 + lh * 8;
    const float* t1 = t0 + 32 * 1024;
#pragma unroll 8
    for (int kt = 0; kt < 32; ++kt) {
      bf16x8_t a0 = cvt8(t0 + kt * 16);
      bf16x8_t a1 = cvt8(t1 + kt * 16);
#pragma unroll
      for (int nt = 0; nt < 4; ++nt) {
        bf16x8_t b = *(const bf16x8_t*)&pack[po + ((kt * 4 + nt) * 64 + lane) * 8];
        acc[0][nt] = mfma_op(a0, b, acc[0][nt]);
        acc[1][nt] = mfma_op(a1, b, acc[1][nt]);
      }
    }
#pragma unroll
    for (int nt = 0; nt < 4; ++nt) {
      const float bias = pb[nt * 32 + l31] + pc[nt * 32 + l31];
#pragma unroll
      for (int mr = 0; mr < 2; ++mr)
#pragma unroll
        for (int r = 0; r < 16; ++r)
          Sd[(mr * 32 + crowf(r)) * PITCH_S + nt * 32 + l31] = (__bf16)(acc[mr][nt][r] + bias);
    }
  }

  // ---------------- transformer layers ----------------
  for (int l = 0; l < 2; ++l) {
    for (int mod = 0; mod < 2; ++mod) {  // 0: update eda (x = imu), 1: update imu (x = updated eda)
      const __bf16* Sx = mod ? Se : Si;
      __bf16* St = mod ? Si : Se;
      const int widx = mod * 2 + l;
      const int attn_po = PO_ATTN + widx * 32 * 512;
      const int ffn1_po = PO_FFN1 + widx * 64 * 512;
      const int ffn2_po = PO_FFN2 + widx * 64 * 512;
      const float* bc  = bc_all + widx * 128;
      const float* b1  = (mod ? ffn_imu_b1 : ffn_eda_b1) + l * 256;
      const float* b2  = (mod ? ffn_imu_b2 : ffn_eda_b2) + l * 128;
      const float* g1  = (mod ? ln_i1g : ln_e1g) + l * 128;
      const float* bb1 = (mod ? ln_i1b : ln_e1b) + l * 128;
      const float* g2  = (mod ? ln_i2g : ln_e2g) + l * 128;
      const float* bb2 = (mod ? ln_i2b : ln_e2b) + l * 128;

      // -- collapsed attention: y = x_other @ Wc^T + bc; then +residual, LN1 --
      f32x16_t acc[2][4] = {};
#pragma unroll
      for (int kt = 0; kt < 8; ++kt) {
        bf16x8_t a0 = *(const bf16x8_t*)&Sx[l31 * PITCH_S + kt * 16 + lh * 8];
        bf16x8_t a1 = *(const bf16x8_t*)&Sx[(32 + l31) * PITCH_S + kt * 16 + lh * 8];
#pragma unroll
        for (int nt = 0; nt < 4; ++nt) {
          bf16x8_t b = *(const bf16x8_t*)&pack[attn_po + ((kt * 4 + nt) * 64 + lane) * 8];
          acc[0][nt] = mfma_op(a0, b, acc[0][nt]);
          acc[1][nt] = mfma_op(a1, b, acc[1][nt]);
        }
      }
#pragma unroll
      for (int nt = 0; nt < 4; ++nt) {
        const float bv = bc[nt * 32 + l31];
#pragma unroll
        for (int mr = 0; mr < 2; ++mr)
#pragma unroll
          for (int r = 0; r < 16; ++r)
            acc[mr][nt][r] += bv + (float)St[(mr * 32 + crowf(r)) * PITCH_S + nt * 32 + l31];
      }
      layer_norm(acc, g1, bb1);
      store_state(acc, St);  // e1 now in St (bf16) AND kept f32 in acc for LN2 residual

      // -- FFN: h = relu(e1 @ W1^T + b1) in 8 col-chunks of 32; y += h @ W2^T --
      f32x16_t yacc[2][4] = {};
#pragma unroll
      for (int hc = 0; hc < 8; ++hc) {
        f32x16_t h0 = {}, h1 = {};
#pragma unroll
        for (int kt = 0; kt < 8; ++kt) {
          bf16x8_t a0 = *(const bf16x8_t*)&St[l31 * PITCH_S + kt * 16 + lh * 8];
          bf16x8_t a1 = *(const bf16x8_t*)&St[(32 + l31) * PITCH_S + kt * 16 + lh * 8];
          bf16x8_t b = *(const bf16x8_t*)&pack[ffn1_po + ((kt * 8 + hc) * 64 + lane) * 8];
          h0 = mfma_op(a0, b, h0);
          h1 = mfma_op(a1, b, h1);
        }
        const float hb = b1[hc * 32 + l31];
#pragma unroll
        for (int r = 0; r < 16; ++r) {
          Sh[crowf(r) * PITCH_H + l31]        = (__bf16)fmaxf(h0[r] + hb, 0.f);
          Sh[(32 + crowf(r)) * PITCH_H + l31] = (__bf16)fmaxf(h1[r] + hb, 0.f);
        }
#pragma unroll
        for (int kt2 = 0; kt2 < 2; ++kt2) {
          bf16x8_t a0 = *(const bf16x8_t*)&Sh[l31 * PITCH_H + kt2 * 16 + lh * 8];
          bf16x8_t a1 = *(const bf16x8_t*)&Sh[(32 + l31) * PITCH_H + kt2 * 16 + lh * 8];
#pragma unroll
          for (int nt = 0; nt < 4; ++nt) {
            bf16x8_t b = *(const bf16x8_t*)&pack[ffn2_po + (((hc * 2 + kt2) * 4 + nt) * 64 + lane) * 8];
            yacc[0][nt] = mfma_op(a0, b, yacc[0][nt]);
            yacc[1][nt] = mfma_op(a1, b, yacc[1][nt]);
          }
        }
      }
#pragma unroll
      for (int nt = 0; nt < 4; ++nt) {
        const float bv = b2[nt * 32 + l31];
#pragma unroll
        for (int mr = 0; mr < 2; ++mr)
#pragma unroll
          for (int r = 0; r < 16; ++r)
            yacc[mr][nt][r] += bv + acc[mr][nt][r];  // f32 residual (e1)
      }
      layer_norm(yacc, g2, bb2);
      store_state(yacc, St);
    }
  }

  // ---------------- head: out = relu(LN(concat(eda,imu) @ out_w^T + out_b)) ----------------
  {
    f32x16_t acc[2][4] = {};
#pragma unroll
    for (int kt = 0; kt < 16; ++kt) {
      const __bf16* Sa = (kt < 8) ? Se : Si;
      const int ko = (kt & 7) * 16 + lh * 8;
      bf16x8_t a0 = *(const bf16x8_t*)&Sa[l31 * PITCH_S + ko];
      bf16x8_t a1 = *(const bf16x8_t*)&Sa[(32 + l31) * PITCH_S + ko];
#pragma unroll
      for (int nt = 0; nt < 4; ++nt) {
        bf16x8_t b = *(const bf16x8_t*)&pack[PO_HEAD + ((kt * 4 + nt) * 64 + lane) * 8];
        acc[0][nt] = mfma_op(a0, b, acc[0][nt]);
        acc[1][nt] = mfma_op(a1, b, acc[1][nt]);
      }
    }
#pragma unroll
    for (int nt = 0; nt < 4; ++nt) {
      const float bv = out_b[nt * 32 + l31];
#pragma unroll
      for (int mr = 0; mr < 2; ++mr)
#pragma unroll
        for (int r = 0; r < 16; ++r) acc[mr][nt][r] += bv;
    }
    layer_norm(acc, out_ln_g, out_ln_b);
#pragma unroll
    for (int nt = 0; nt < 4; ++nt)
#pragma unroll
      for (int mr = 0; mr < 2; ++mr)
#pragma unroll
        for (int r = 0; r < 16; ++r)
          out[(rowbase + mr * 32 + crowf(r)) * 128 + nt * 32 + l31] = fmaxf(acc[mr][nt][r], 0.f);
  }
}

// ---------------------------------------------------------------------------
extern "C" void kernel_launch(void* const* d_in, const int* in_sizes, int n_in,
                              void* d_out, int out_size, void* d_ws, size_t ws_size,
                              hipStream_t stream) {
  const float* tokens     = (const float*)d_in[0];
  const float* eda_proj_w = (const float*)d_in[1];
  const float* eda_proj_b = (const float*)d_in[2];
  const float* imu_proj_w = (const float*)d_in[3];
  const float* imu_proj_b = (const float*)d_in[4];
  const float* eda_cls    = (const float*)d_in[5];
  const float* imu_cls    = (const float*)d_in[6];
  const float* e2i_wqkv   = (const float*)d_in[7];
  const float* e2i_bqkv   = (const float*)d_in[8];
  const float* e2i_wo     = (const float*)d_in[9];
  const float* e2i_bo     = (const float*)d_in[10];
  const float* i2e_wqkv   = (const float*)d_in[11];
  const float* i2e_bqkv   = (const float*)d_in[12];
  const float* i2e_wo     = (const float*)d_in[13];
  const float* i2e_bo     = (const float*)d_in[14];
  const float* ffn_eda_w1 = (const float*)d_in[15];
  const float* ffn_eda_b1 = (const float*)d_in[16];
  const float* ffn_eda_w2 = (const float*)d_in[17];
  const float* ffn_eda_b2 = (const float*)d_in[18];
  const float* ffn_imu_w1 = (const float*)d_in[19];
  const float* ffn_imu_b1 = (const float*)d_in[20];
  const float* ffn_imu_w2 = (const float*)d_in[21];
  const float* ffn_imu_b2 = (const float*)d_in[22];
  const float* ln_eda1_g  = (const float*)d_in[23];
  const float* ln_eda1_b  = (const float*)d_in[24];
  const float* ln_eda2_g  = (const float*)d_in[25];
  const float* ln_eda2_b  = (const float*)d_in[26];
  const float* ln_imu1_g  = (const float*)d_in[27];
  const float* ln_imu1_b  = (const float*)d_in[28];
  const float* ln_imu2_g  = (const float*)d_in[29];
  const float* ln_imu2_b  = (const float*)d_in[30];
  const float* out_w      = (const float*)d_in[31];
  const float* out_b      = (const float*)d_in[32];
  const float* out_ln_g   = (const float*)d_in[33];
  const float* out_ln_b   = (const float*)d_in[34];

  float*  wsf  = (float*)d_ws;
  __bf16* pack = (__bf16*)((char*)d_ws + WS_PACK_BYTE);

  prep_combine<<<dim3(512), dim3(64), 0, stream>>>(
      e2i_wqkv, e2i_wo, e2i_bqkv, e2i_bo,
      i2e_wqkv, i2e_wo, i2e_bqkv, i2e_bo, wsf);

  prep_pack<<<dim3(960), dim3(64), 0, stream>>>(
      eda_proj_w, imu_proj_w, ffn_eda_w1, ffn_imu_w1,
      ffn_eda_w2, ffn_imu_w2, out_w, wsf, pack);

  fused_fwd<<<dim3(1024), dim3(64), 0, stream>>>(
      tokens, eda_proj_b, eda_cls, imu_proj_b, imu_cls,
      ffn_eda_b1, ffn_eda_b2, ffn_imu_b1, ffn_imu_b2,
      ln_eda1_g, ln_eda1_b, ln_eda2_g, ln_eda2_b,
      ln_imu1_g, ln_imu1_b, ln_imu2_g, ln_imu2_b,
      out_b, out_ln_g, out_ln_b,
      wsf + WS_BC_F, pack, (float*)d_out);
}

// Round 6
// 653.110 us; speedup vs baseline: 1.2931x; 1.2931x over previous
//
#include <hip/hip_runtime.h>
#include <hip/hip_bf16.h>

// ---------------------------------------------------------------------------
// EDACrossIMUEncoder fused forward (MI355X / gfx950) — v3
//
// Seq-len == 1  =>  softmax(1x1) == 1  =>  MHA(q,k) == k @ (Wo Wv)^T + (Wo bv + bo).
// v1 (522us, passed 0.031): fully-unrolled ~240KB code, I$-thrash, 4 waves/CU.
// v2 (failed 0.241): rolled loops + MR=1 + launch_bounds(64,2); index-audited
//   4x identical math to v1 => suspect f32x16 spill codegen at the 256-VGPR cap
//   (~240 live regs in FFN phase; rule #19/#20 territory).
// v3: keep rolled loops + MR=1 + 8 blocks/CU, but cut peak pressure to ~140:
//   - biases/residuals folded into MFMA C-init (no post-pass; acc dead early)
//   - no af[] register preload (re-read St per hc, like v1)
// 32x32x16 bf16 MFMA layouts (learn_hip m74/m101 verified):
//   A: row = lane&31, k = (lane>>5)*8 + j
//   B: col = lane&31, k = (lane>>5)*8 + j
//   C/D: col = lane&31, row = (r&3) + 8*(r>>2) + 4*(lane>>5), r = 0..15
// Requires ws_size >= 1.25 MB.
// ---------------------------------------------------------------------------

typedef __bf16 bf16x8_t __attribute__((ext_vector_type(8)));
typedef float  f32x16_t __attribute__((ext_vector_type(16)));
typedef float  f32x4_t  __attribute__((ext_vector_type(4)));

#define DEV static __device__ __forceinline__

DEV f32x16_t mfma_op(bf16x8_t a, bf16x8_t b, f32x16_t c) {
  return __builtin_amdgcn_mfma_f32_32x32x16_bf16(a, b, c, 0, 0, 0);
}

DEV bf16x8_t cvt8(const float* p) {
  f32x4_t t0 = *(const f32x4_t*)p;
  f32x4_t t1 = *(const f32x4_t*)(p + 4);
  bf16x8_t a;
  a[0] = (__bf16)t0[0]; a[1] = (__bf16)t0[1]; a[2] = (__bf16)t0[2]; a[3] = (__bf16)t0[3];
  a[4] = (__bf16)t1[0]; a[5] = (__bf16)t1[1]; a[6] = (__bf16)t1[2]; a[7] = (__bf16)t1[3];
  return a;
}

// ---- packed-weight element offsets (bf16 elems; one chunk = 64 lanes x 8 = 512) ----
constexpr int PO_PROJ_E = 0;                     // K=512 N=128 : 128 chunks
constexpr int PO_PROJ_I = PO_PROJ_E + 128 * 512;
constexpr int PO_ATTN   = PO_PROJ_I + 128 * 512; // 4 x (K=128 N=128 : 32 chunks) [e2i l0, e2i l1, i2e l0, i2e l1]
constexpr int PO_FFN1   = PO_ATTN   + 4 * 32 * 512; // 4 x (K=128 N=256 : 64 chunks)
constexpr int PO_FFN2   = PO_FFN1   + 4 * 64 * 512; // 4 x (K=256 N=128 : 64 chunks)
constexpr int PO_HEAD   = PO_FFN2   + 4 * 64 * 512; // K=256 N=128 : 64 chunks
constexpr int WS_BC_F      = 4 * 128 * 128;          // float index of combined bias region
constexpr int WS_PACK_BYTE = (WS_BC_F + 4 * 128) * 4; // = 264192 (16B aligned)

#define PITCH_S 136   // bf16 elems per row of state scratch (128 + 8 pad); 272B = 17*16
#define PITCH_H 40    // bf16 elems per row of FFN-h scratch  (32 + 8 pad);  80B = 5*16

// ---------------------------------------------------------------------------
// prep 1: fold attention:  Wc = Wo @ Wv (f32),  bc = Wo @ bv + bo
// ---------------------------------------------------------------------------
__global__ __launch_bounds__(64) void prep_combine(
    const float* __restrict__ e2i_wqkv, const float* __restrict__ e2i_wo,
    const float* __restrict__ e2i_bqkv, const float* __restrict__ e2i_bo,
    const float* __restrict__ i2e_wqkv, const float* __restrict__ i2e_wo,
    const float* __restrict__ i2e_bqkv, const float* __restrict__ i2e_bo,
    float* __restrict__ wsf) {
  const int blk = blockIdx.x;
  const int d = blk >> 7, n = blk & 127, l = d & 1;
  const float* wqkv = (d < 2) ? e2i_wqkv : i2e_wqkv;
  const float* wo   = (d < 2) ? e2i_wo   : i2e_wo;
  const float* bqkv = (d < 2) ? e2i_bqkv : i2e_bqkv;
  const float* bo   = (d < 2) ? e2i_bo   : i2e_bo;
  const float* wv    = wqkv + l * 3 * 128 * 128 + 2 * 128 * 128; // wqkv[2M:3M]
  const float* worow = wo + l * 128 * 128 + n * 128;
  const float* bv    = bqkv + l * 3 * 128 + 2 * 128;
  const int lane = threadIdx.x;
  float a0 = 0.f, a1 = 0.f;
  for (int p = 0; p < 128; ++p) {
    float w = worow[p];
    a0 += w * wv[p * 128 + lane];
    a1 += w * wv[p * 128 + 64 + lane];
  }
  wsf[d * 16384 + n * 128 + lane]      = a0;
  wsf[d * 16384 + n * 128 + 64 + lane] = a1;
  float bacc = worow[lane] * bv[lane] + worow[64 + lane] * bv[64 + lane];
  for (int off = 1; off < 64; off <<= 1) bacc += __shfl_xor(bacc, off, 64);
  if (lane == 0) wsf[WS_BC_F + d * 128 + n] = bacc + bo[l * 128 + n];
}

// ---------------------------------------------------------------------------
// prep 2: pack all weights into bf16 B-fragment order.
// ---------------------------------------------------------------------------
__global__ __launch_bounds__(64) void prep_pack(
    const float* __restrict__ proj_e, const float* __restrict__ proj_i,
    const float* __restrict__ ffn_e_w1, const float* __restrict__ ffn_i_w1,
    const float* __restrict__ ffn_e_w2, const float* __restrict__ ffn_i_w2,
    const float* __restrict__ out_w, const float* __restrict__ wsf,
    __bf16* __restrict__ pack) {
  const int b = blockIdx.x, lane = threadIdx.x;
  const float* src; int K, sh, dstOff, c; // sh: log2(NT)
  if (b < 128)      { src = proj_e; K = 512; sh = 2; dstOff = PO_PROJ_E; c = b; }
  else if (b < 256) { src = proj_i; K = 512; sh = 2; dstOff = PO_PROJ_I; c = b - 128; }
  else if (b < 384) { int i = (b - 256) >> 5; c = (b - 256) & 31;
                      src = wsf + i * 16384; K = 128; sh = 2;
                      dstOff = PO_ATTN + i * 32 * 512; }
  else if (b < 640) { int i = (b - 384) >> 6; c = (b - 384) & 63;
                      src = ((i < 2) ? ffn_e_w1 : ffn_i_w1) + (i & 1) * 256 * 128;
                      K = 128; sh = 3; dstOff = PO_FFN1 + i * 64 * 512; }
  else if (b < 896) { int i = (b - 640) >> 6; c = (b - 640) & 63;
                      src = ((i < 2) ? ffn_e_w2 : ffn_i_w2) + (i & 1) * 128 * 256;
                      K = 256; sh = 2; dstOff = PO_FFN2 + i * 64 * 512; }
  else              { c = b - 896; src = out_w; K = 256; sh = 2; dstOff = PO_HEAD; }
  const int kt = c >> sh, nt = c & ((1 << sh) - 1);
  const int n  = nt * 32 + (lane & 31);
  const int kb = kt * 16 + (lane >> 5) * 8;
  const float* s = src + n * K + kb;
  bf16x8_t v;
#pragma unroll
  for (int j = 0; j < 8; ++j) v[j] = (__bf16)s[j];
  *(bf16x8_t*)&pack[dstOff + (c * 64 + lane) * 8] = v;
}

// ---------------------------------------------------------------------------
// main fused kernel v3: 2048 blocks x 64 threads (1 wave = 32 batch rows).
// LDS 19968B -> 8 blocks/CU (2 waves/SIMD). Rolled loops -> I$-resident code.
// Peak VGPR ~140 (bias/residual folded into MFMA C-init; no reg preloads).
// ---------------------------------------------------------------------------
__global__ __launch_bounds__(64, 2) void fused_fwd(
    const float* __restrict__ tokens,
    const float* __restrict__ eda_proj_b, const float* __restrict__ eda_cls,
    const float* __restrict__ imu_proj_b, const float* __restrict__ imu_cls,
    const float* __restrict__ ffn_eda_b1, const float* __restrict__ ffn_eda_b2,
    const float* __restrict__ ffn_imu_b1, const float* __restrict__ ffn_imu_b2,
    const float* __restrict__ ln_e1g, const float* __restrict__ ln_e1b,
    const float* __restrict__ ln_e2g, const float* __restrict__ ln_e2b,
    const float* __restrict__ ln_i1g, const float* __restrict__ ln_i1b,
    const float* __restrict__ ln_i2g, const float* __restrict__ ln_i2b,
    const float* __restrict__ out_b, const float* __restrict__ out_ln_g,
    const float* __restrict__ out_ln_b,
    const float* __restrict__ bc_all,          // [4][128] combined attn bias
    const __bf16* __restrict__ pack,
    float* __restrict__ out) {
  alignas(16) __shared__ __bf16 smem[2 * 32 * PITCH_S + 32 * PITCH_H];
  __bf16* Se = smem;
  __bf16* Si = smem + 32 * PITCH_S;
  __bf16* Sh = smem + 2 * 32 * PITCH_S;

  const int lane = threadIdx.x;
  const int l31 = lane & 31, lh = lane >> 5;
  const int rowbase = blockIdx.x * 32;

  auto crowf = [&](int r) { return (r & 3) + ((r >> 2) << 3) + (lh << 2); };

  auto layer_norm = [&](f32x16_t (&A)[4], const float* g, const float* bb) {
    float gv[4], bv[4];
#pragma unroll
    for (int nt = 0; nt < 4; ++nt) { gv[nt] = g[nt * 32 + l31]; bv[nt] = bb[nt * 32 + l31]; }
#pragma unroll
    for (int r = 0; r < 16; ++r) {
      float s = 0.f, s2 = 0.f;
#pragma unroll
      for (int nt = 0; nt < 4; ++nt) { float v = A[nt][r]; s += v; s2 += v * v; }
#pragma unroll
      for (int off = 1; off < 32; off <<= 1) {
        s  += __shfl_xor(s, off, 64);
        s2 += __shfl_xor(s2, off, 64);
      }
      const float mean = s * (1.f / 128.f);
      const float var  = s2 * (1.f / 128.f) - mean * mean;
      const float rs   = rsqrtf(var + 1e-5f);
#pragma unroll
      for (int nt = 0; nt < 4; ++nt)
        A[nt][r] = (A[nt][r] - mean) * rs * gv[nt] + bv[nt];
    }
  };

  auto store_state = [&](f32x16_t (&A)[4], __bf16* S) {
#pragma unroll
    for (int nt = 0; nt < 4; ++nt)
#pragma unroll
      for (int r = 0; r < 16; ++r)
        S[crowf(r) * PITCH_S + nt * 32 + l31] = (__bf16)A[nt][r];
  };

  // ---------------- projections: state = tok @ Wproj^T + b + cls ----------------
#pragma unroll 1
  for (int sel = 0; sel < 2; ++sel) {
    const float* pb = sel ? imu_proj_b : eda_proj_b;
    const float* pc = sel ? imu_cls : eda_cls;
    __bf16* Sd = sel ? Si : Se;
    const __bf16* pw = pack + (sel ? PO_PROJ_I : PO_PROJ_E);
    f32x16_t acc[4];
#pragma unroll
    for (int nt = 0; nt < 4; ++nt) {
      const float bias = pb[nt * 32 + l31] + pc[nt * 32 + l31];
#pragma unroll
      for (int r = 0; r < 16; ++r) acc[nt][r] = bias;
    }
    const float* t0 = tokens + (size_t)(rowbase + l31) * 1024 + sel * 512 + lh * 8;
#pragma unroll 1
    for (int kt = 0; kt < 32; ++kt) {
      bf16x8_t a0 = cvt8(t0 + kt * 16);
      const __bf16* pwk = pw + (kt * 4 * 64 + lane) * 8;
#pragma unroll
      for (int nt = 0; nt < 4; ++nt)
        acc[nt] = mfma_op(a0, *(const bf16x8_t*)(pwk + nt * 512), acc[nt]);
    }
    store_state(acc, Sd);
  }

  // ---------------- transformer layers ----------------
#pragma unroll 1
  for (int l = 0; l < 2; ++l) {
#pragma unroll 1
    for (int mod = 0; mod < 2; ++mod) {  // 0: update eda (x = imu), 1: update imu (x = updated eda)
      const __bf16* Sx = mod ? Se : Si;
      __bf16* St = mod ? Si : Se;
      const int widx = mod * 2 + l;
      const __bf16* attn_w = pack + PO_ATTN + widx * 32 * 512;
      const __bf16* ffn1_w = pack + PO_FFN1 + widx * 64 * 512;
      const __bf16* ffn2_w = pack + PO_FFN2 + widx * 64 * 512;
      const float* bc  = bc_all + widx * 128;
      const float* b1  = (mod ? ffn_imu_b1 : ffn_eda_b1) + l * 256;
      const float* b2  = (mod ? ffn_imu_b2 : ffn_eda_b2) + l * 128;
      const float* g1  = (mod ? ln_i1g : ln_e1g) + l * 128;
      const float* bb1 = (mod ? ln_i1b : ln_e1b) + l * 128;
      const float* g2  = (mod ? ln_i2g : ln_e2g) + l * 128;
      const float* bb2 = (mod ? ln_i2b : ln_e2b) + l * 128;

      // -- collapsed attention: acc init = bc + residual; += x_other @ Wc^T; LN1 --
      f32x16_t acc[4];
#pragma unroll
      for (int nt = 0; nt < 4; ++nt) {
        const float bv = bc[nt * 32 + l31];
#pragma unroll
        for (int r = 0; r < 16; ++r)
          acc[nt][r] = bv + (float)St[crowf(r) * PITCH_S + nt * 32 + l31];
      }
#pragma unroll 1
      for (int kt = 0; kt < 8; ++kt) {
        bf16x8_t a0 = *(const bf16x8_t*)&Sx[l31 * PITCH_S + kt * 16 + lh * 8];
        const __bf16* wk = attn_w + (kt * 4 * 64 + lane) * 8;
#pragma unroll
        for (int nt = 0; nt < 4; ++nt)
          acc[nt] = mfma_op(a0, *(const bf16x8_t*)(wk + nt * 512), acc[nt]);
      }
      layer_norm(acc, g1, bb1);
      store_state(acc, St);  // e1 in LDS (A-layout source) AND in acc (f32)

      // -- FFN: yacc init = b2 + e1 (frees acc); h per 32-col chunk --
      f32x16_t yacc[4];
#pragma unroll
      for (int nt = 0; nt < 4; ++nt) {
        const float bv = b2[nt * 32 + l31];
#pragma unroll
        for (int r = 0; r < 16; ++r) yacc[nt][r] = bv + acc[nt][r];
      }
#pragma unroll 1
      for (int hc = 0; hc < 8; ++hc) {
        f32x16_t h;
        {
          const float hb = b1[hc * 32 + l31];
#pragma unroll
          for (int r = 0; r < 16; ++r) h[r] = hb;
        }
        const __bf16* w1k = ffn1_w + (hc * 64 + lane) * 8;
#pragma unroll
        for (int kt = 0; kt < 8; ++kt) {
          bf16x8_t a0 = *(const bf16x8_t*)&St[l31 * PITCH_S + kt * 16 + lh * 8];
          h = mfma_op(a0, *(const bf16x8_t*)(w1k + kt * 8 * 512), h);
        }
#pragma unroll
        for (int r = 0; r < 16; ++r)
          Sh[crowf(r) * PITCH_H + l31] = (__bf16)fmaxf(h[r], 0.f);
#pragma unroll
        for (int kt2 = 0; kt2 < 2; ++kt2) {
          bf16x8_t ah = *(const bf16x8_t*)&Sh[l31 * PITCH_H + kt2 * 16 + lh * 8];
          const __bf16* w2k = ffn2_w + (((hc * 2 + kt2) * 4) * 64 + lane) * 8;
#pragma unroll
          for (int nt = 0; nt < 4; ++nt)
            yacc[nt] = mfma_op(ah, *(const bf16x8_t*)(w2k + nt * 512), yacc[nt]);
        }
      }
      layer_norm(yacc, g2, bb2);
      store_state(yacc, St);
    }
  }

  // ---------------- head: out = relu(LN(concat(eda,imu) @ out_w^T + out_b)) ----------------
  {
    f32x16_t acc[4];
#pragma unroll
    for (int nt = 0; nt < 4; ++nt) {
      const float bv = out_b[nt * 32 + l31];
#pragma unroll
      for (int r = 0; r < 16; ++r) acc[nt][r] = bv;
    }
#pragma unroll 1
    for (int kt = 0; kt < 16; ++kt) {
      const __bf16* Sa = (kt < 8) ? Se : Si;
      const int ko = (kt & 7) * 16 + lh * 8;
      bf16x8_t a0 = *(const bf16x8_t*)&Sa[l31 * PITCH_S + ko];
      const __bf16* wk = pack + PO_HEAD + (kt * 4 * 64 + lane) * 8;
#pragma unroll
      for (int nt = 0; nt < 4; ++nt)
        acc[nt] = mfma_op(a0, *(const bf16x8_t*)(wk + nt * 512), acc[nt]);
    }
    layer_norm(acc, out_ln_g, out_ln_b);
#pragma unroll
    for (int nt = 0; nt < 4; ++nt)
#pragma unroll
      for (int r = 0; r < 16; ++r)
        out[(rowbase + crowf(r)) * 128 + nt * 32 + l31] = fmaxf(acc[nt][r], 0.f);
  }
}

// ---------------------------------------------------------------------------
extern "C" void kernel_launch(void* const* d_in, const int* in_sizes, int n_in,
                              void* d_out, int out_size, void* d_ws, size_t ws_size,
                              hipStream_t stream) {
  const float* tokens     = (const float*)d_in[0];
  const float* eda_proj_w = (const float*)d_in[1];
  const float* eda_proj_b = (const float*)d_in[2];
  const float* imu_proj_w = (const float*)d_in[3];
  const float* imu_proj_b = (const float*)d_in[4];
  const float* eda_cls    = (const float*)d_in[5];
  const float* imu_cls    = (const float*)d_in[6];
  const float* e2i_wqkv   = (const float*)d_in[7];
  const float* e2i_bqkv   = (const float*)d_in[8];
  const float* e2i_wo     = (const float*)d_in[9];
  const float* e2i_bo     = (const float*)d_in[10];
  const float* i2e_wqkv   = (const float*)d_in[11];
  const float* i2e_bqkv   = (const float*)d_in[12];
  const float* i2e_wo     = (const float*)d_in[13];
  const float* i2e_bo     = (const float*)d_in[14];
  const float* ffn_eda_w1 = (const float*)d_in[15];
  const float* ffn_eda_b1 = (const float*)d_in[16];
  const float* ffn_eda_w2 = (const float*)d_in[17];
  const float* ffn_eda_b2 = (const float*)d_in[18];
  const float* ffn_imu_w1 = (const float*)d_in[19];
  const float* ffn_imu_b1 = (const float*)d_in[20];
  const float* ffn_imu_w2 = (const float*)d_in[21];
  const float* ffn_imu_b2 = (const float*)d_in[22];
  const float* ln_eda1_g  = (const float*)d_in[23];
  const float* ln_eda1_b  = (const float*)d_in[24];
  const float* ln_eda2_g  = (const float*)d_in[25];
  const float* ln_eda2_b  = (const float*)d_in[26];
  const float* ln_imu1_g  = (const float*)d_in[27];
  const float* ln_imu1_b  = (const float*)d_in[28];
  const float* ln_imu2_g  = (const float*)d_in[29];
  const float* ln_imu2_b  = (const float*)d_in[30];
  const float* out_w      = (const float*)d_in[31];
  const float* out_b      = (const float*)d_in[32];
  const float* out_ln_g   = (const float*)d_in[33];
  const float* out_ln_b   = (const float*)d_in[34];

  float*  wsf  = (float*)d_ws;
  __bf16* pack = (__bf16*)((char*)d_ws + WS_PACK_BYTE);

  prep_combine<<<dim3(512), dim3(64), 0, stream>>>(
      e2i_wqkv, e2i_wo, e2i_bqkv, e2i_bo,
      i2e_wqkv, i2e_wo, i2e_bqkv, i2e_bo, wsf);

  prep_pack<<<dim3(960), dim3(64), 0, stream>>>(
      eda_proj_w, imu_proj_w, ffn_eda_w1, ffn_imu_w1,
      ffn_eda_w2, ffn_imu_w2, out_w, wsf, pack);

  fused_fwd<<<dim3(2048), dim3(64), 0, stream>>>(
      tokens, eda_proj_b, eda_cls, imu_proj_b, imu_cls,
      ffn_eda_b1, ffn_eda_b2, ffn_imu_b1, ffn_imu_b2,
      ln_eda1_g, ln_eda1_b, ln_eda2_g, ln_eda2_b,
      ln_imu1_g, ln_imu1_b, ln_imu2_g, ln_imu2_b,
      out_b, out_ln_g, out_ln_b,
      wsf + WS_BC_F, pack, (float*)d_out);
}